// Round 8
// baseline (95.006 us; speedup 1.0000x reference)
//
#include <hip/hip_runtime.h>
#include <cfloat>
#include <cmath>

#define NROI 2000
#define NCLS 81
#define META 93
#define NMS_TAU 0.3f
#define MINCONF 0.7f
#define MAXDET 100
#define SORTN 2048

typedef unsigned long long u64;

// pack layout: [63:32]=dk (ascending == score descending), [17:7]=roi idx, [6:0]=class
// idx more significant than cls -> tie order identical to (key desc, idx asc).
#define PADPACK(j) (0xC000000000000000ull | (u64)((unsigned)(j) << 7))

// ============ Kernel A: per-roi refine, 8 threads per roi ============
__global__ __launch_bounds__(256) void refine_kernel(const float* __restrict__ rois,
                                                     const float* __restrict__ probs,
                                                     const float* __restrict__ deltas,
                                                     const float* __restrict__ meta,
                                                     float4* __restrict__ wbox,
                                                     u64* __restrict__ wpack,
                                                     int total) {
#pragma clang fp contract(off)
    const int tid = threadIdx.x;
    const int r = tid & 7;                      // scanner lane within roi-group
    const int t = blockIdx.x * 32 + (tid >> 3); // roi id
    if (t >= total) return;
    const int b = t / NROI;
    const int j = t - b * NROI;

    const float* p = probs + (size_t)t * NCLS;
    float best = p[r];
    int bi = r;
    for (int c = r + 8; c < NCLS; c += 8) {
        float v = p[c];
        if (v > best) { best = v; bi = c; }     // ascending c -> first max kept
    }
    // reduce across the 8 scanner lanes (same roi): max value, first index on tie
    for (int m = 1; m < 8; m <<= 1) {
        float v2 = __shfl_xor(best, m);
        int i2 = __shfl_xor(bi, m);
        if (v2 > best || (v2 == best && i2 < bi)) { best = v2; bi = i2; }
    }
    if (r != 0) return;

    const float* dp = deltas + ((size_t)t * NCLS + bi) * 4;
    float4 dd = *(const float4*)dp;
    float d0 = dd.x * 0.1f, d1 = dd.y * 0.1f, d2 = dd.z * 0.2f, d3 = dd.w * 0.2f;
    float4 rr = *(const float4*)(rois + (size_t)t * 4);
    float r0 = rr.x, r1 = rr.y, r2 = rr.z, r3 = rr.w;
    float h = r2 - r0, w = r3 - r1;
    float cy = (r0 + 0.5f * h) + d0 * h;
    float cx = (r1 + 0.5f * w) + d1 * w;
    float h2 = h * expf(d2);
    float w2 = w * expf(d3);
    float y1 = cy - 0.5f * h2, x1 = cx - 0.5f * w2;
    float y2 = y1 + h2, x2 = x1 + w2;

    const float sy = meta[4] - 1.0f;
    const float sx = meta[5] - 1.0f;
    const float* mb = meta + (size_t)b * META;
    const float wy1 = (mb[7] - 0.0f) / sy;
    const float wx1 = (mb[8] - 0.0f) / sx;
    const float wy2 = (mb[9] - 1.0f) / sy;
    const float wx2 = (mb[10] - 1.0f) / sx;
    y1 = fminf(fmaxf(y1, wy1), wy2);
    x1 = fminf(fmaxf(x1, wx1), wx2);
    y2 = fminf(fmaxf(y2, wy1), wy2);
    x2 = fminf(fmaxf(x2, wx1), wx2);

    bool valid = (bi > 0) && (best >= MINCONF);
    float key = valid ? best : -1.0f;
    unsigned kb = __float_as_uint(key);
    unsigned ip = (kb & 0x80000000u) ? ~kb : (kb | 0x80000000u);
    unsigned dk = ~ip;                          // ascending dk == descending key
    wbox[t] = make_float4(y1, x1, y2, x2);
    wpack[(size_t)b * SORTN + j] = ((u64)dk << 32) | (unsigned)(j << 7) | (unsigned)bi;
}

// ============ Kernel B: register sort + rank-merge + pairwise NMS + top-k ============
__global__ __launch_bounds__(1024) void merge_nms_kernel(const float4* __restrict__ wbox,
                                                         const u64* __restrict__ wpack,
                                                         float* __restrict__ out) {
#pragma clang fp contract(off)
    __shared__ u64 s_pack[SORTN];                 // 16 KB
    __shared__ float4 s_boxArena[NROI];           // 32 KB (aliased as merge temp)
    __shared__ unsigned char s_keep[SORTN];       // 2 KB
    // chunk-candidate staging (SoA, conflict-free lane reads)
    __shared__ float s_cy1[64], s_cx1[64], s_cy2[64], s_cx2[64], s_car[64];
    __shared__ int s_ccl[64], s_init[64];
    __shared__ u64 s_sup[64];
    __shared__ u64 s_clsmask[NCLS];               // per-class alive bitmask
    __shared__ u64 s_alive;
    __shared__ int s_scan[17];
    __shared__ int s_total, s_V;

    u64* s_tmp = (u64*)s_boxArena;                // alias, used pre-box-load
    float4* s_box = s_boxArena;

    const int b = blockIdx.x;
    const int tid = threadIdx.x;
    const int lane = tid & 63;
    const int wv = tid >> 6;                      // wave id 0..15

    // ---- register-prefetch boxes (HBM latency overlaps sort+merge below) ----
    float4 rb0 = wbox[b * NROI + tid];            // tid < 1024 < NROI always
    float4 rb1;
    const int bj1 = tid + 1024;
    if (bj1 < NROI) rb1 = wbox[b * NROI + bj1];

    // ---- load 2 packed keys/thread: elements g0=128*wv+2*lane, g1=g0+1 ----
    const u64* wp = wpack + (size_t)b * SORTN;
    const int g0 = (wv << 7) + (lane << 1);
    const int g1 = g0 + 1;
    u64 v0, v1;
    if (wv < 15) {                                // wave-uniform: no pads here
        ulonglong2 ld = *(const ulonglong2*)(wp + g0);
        v0 = ld.x; v1 = ld.y;
    } else {
        v0 = (g0 < NROI) ? wp[g0] : PADPACK(g0);
        v1 = (g1 < NROI) ? wp[g1] : PADPACK(g1);
    }

    // ---- wave-local register bitonic: each wave sorts its 128-run ascending ----
    // element le = 2*lane + r; asc(k) = ((le&k)==0) == ((lane&(k>>1))==0);
    // partner for jj>=2 is lane^(jj>>1) same r; jj==1 is the in-thread pair.
    for (int k = 2; k <= 128; k <<= 1) {
        const bool asc = ((lane & (k >> 1)) == 0);
        for (int jj = k >> 1; jj >= 2; jj >>= 1) {
            const int d = jj >> 1;
            u64 p0 = __shfl_xor(v0, d);
            u64 p1 = __shfl_xor(v1, d);
            const bool lower = ((lane & d) == 0);
            const bool keepmin = (lower == asc);
            v0 = ((v0 < p0) == keepmin) ? v0 : p0;
            v1 = ((v1 < p1) == keepmin) ? v1 : p1;
        }
        u64 lo = (v0 < v1) ? v0 : v1;
        u64 hi = (v0 < v1) ? v1 : v0;
        v0 = asc ? lo : hi;
        v1 = asc ? hi : lo;
    }
    s_pack[g0] = v0;
    s_pack[g1] = v1;
    __syncthreads();

    // ---- rank-merge rounds: 128 -> 256 -> 512 -> 1024 -> 2048 (ping-pong) ----
    // keys unique (idx in low bits) -> strict lower_bound is collision-free.
    {
        u64* src = s_pack;
        u64* dst = s_tmp;
#pragma unroll
        for (int s = 7; s <= 10; ++s) {           // L = 1<<s
            const int L = 1 << s;
            for (int i = tid; i < SORTN; i += 1024) {
                u64 x = src[i];
                int run = i >> s, local = i & (L - 1);
                int pbase = (run ^ 1) << s;
                int lo = 0, hi = L;
                while (lo < hi) {
                    int mid = (lo + hi) >> 1;
                    if (src[pbase + mid] < x) lo = mid + 1; else hi = mid;
                }
                dst[((run >> 1) << (s + 1)) + local + lo] = x;
            }
            __syncthreads();
            u64* t2 = src; src = dst; dst = t2;
        }
        // 4 rounds (even) -> final data back in s_pack
    }

    // ---- store prefetched boxes (overwrites s_tmp region), find V, init keep ----
    s_box[tid] = rb0;
    if (bj1 < NROI) s_box[bj1] = rb1;
    if (tid == 0) {
        int lo = 0, hi = SORTN;
        while (lo < hi) {
            int mid = (lo + hi) >> 1;
            if (!(s_pack[mid] >> 63)) lo = mid + 1; else hi = mid;
        }
        s_V = lo;
        s_total = 0;
    }
    __syncthreads();
    const int V = s_V;
    for (int j = tid; j < SORTN; j += 1024) s_keep[j] = (j < V) ? 1 : 0;
    __syncthreads();

    // ---- blocked greedy NMS: pairwise matrix + sparse exact resolve ----
    // class-skip is EXACT: different classes have offset diff >= 2 while
    // clipped boxes lie in [0,1] -> intersection height <= -1 -> IoU == 0.
    for (int c = 0; c < V; c += 64) {
        bool init_flag = false;
        if (tid < 64) {
            int j = c + tid;
            int cl = -1;
            float y1 = 0.f, x1 = 0.f, y2 = 0.f, x2 = 0.f, ar = 0.f;
            if (j < V) {
                init_flag = (s_keep[j] != 0);
                u64 pk = s_pack[j];
                int o = (int)((pk >> 7) & 0x7FF);
                cl = (int)(pk & 0x7F);
                float4 bx = s_box[o];
                float off = (float)cl * 2.0f;
                // area from OFFSETTED coords (matches reference fp rounding)
                y1 = bx.x + off; x1 = bx.y + off; y2 = bx.z + off; x2 = bx.w + off;
                ar = (y2 - y1) * (x2 - x1);
            }
            s_cy1[tid] = y1; s_cx1[tid] = x1; s_cy2[tid] = y2; s_cx2[tid] = x2;
            s_car[tid] = ar; s_ccl[tid] = cl; s_init[tid] = init_flag ? 1 : 0;
        } else if (tid >= 64 && tid < 64 + NCLS) {
            s_clsmask[tid - 64] = 0ull;           // zero class masks in parallel
        }
        __syncthreads();

        // pairwise suppression matrix: wave w handles rows w, w+16, w+32, w+48
        {
            int i = tid & 63;
            int w = tid >> 6;
            float iy1 = s_cy1[i], ix1 = s_cx1[i], iy2 = s_cy2[i], ix2 = s_cx2[i];
            float iar = s_car[i];
            int icl = s_ccl[i], iin = s_init[i];
#pragma unroll
            for (int p = 0; p < 4; ++p) {
                int jr = w + (p << 4);
                float jy1 = s_cy1[jr], jx1 = s_cx1[jr], jy2 = s_cy2[jr], jx2 = s_cx2[jr];
                float jar = s_car[jr];
                int jcl = s_ccl[jr], jin = s_init[jr];
                bool bit = false;
                if (i < jr && iin && jin && icl == jcl) {
                    float ih = fmaxf(fminf(jy2, iy2) - fmaxf(jy1, iy1), 0.0f);
                    float iw = fmaxf(fminf(jx2, ix2) - fmaxf(jx1, ix1), 0.0f);
                    float inter = ih * iw;
                    float iou = inter / ((jar + iar - inter) + 1e-8f);
                    bit = iou > NMS_TAU;
                }
                u64 m = __ballot(bit);
                if (i == 0) s_sup[jr] = m;
            }
        }
        __syncthreads();

        // exact sequential resolve on wave 0 (sparse fast path) + class masks
        if (tid < 64) {
            u64 sup = s_sup[tid];
            u64 initm = __ballot(init_flag);
            u64 hasup = __ballot(init_flag && sup != 0ull);
            u64 alive = initm & ~hasup;          // no-suppressor entries kept outright
            u64 m = hasup;
            while (m) {                           // usually 0-4 iterations
                int t2 = __ffsll((unsigned long long)m) - 1;
                m &= m - 1;
                u64 st = __shfl(sup, t2);         // sup_t only has bits < t2
                if ((st & alive) == 0ull) alive |= (1ull << t2);
            }
            s_keep[c + tid] = (unsigned char)((alive >> tid) & 1ull);
            if ((alive >> tid) & 1ull)
                atomicOr(&s_clsmask[s_ccl[tid]], 1ull << tid);
            if (tid == 0) { s_alive = alive; s_total += __popcll(alive); }
        }
        __syncthreads();
        if (s_total >= MAXDET) break;  // tail ranks >= 100, never output

        // suppress remaining entries against this chunk's kept set
        if (s_alive) {
            for (int j = c + 64 + tid; j < V; j += 1024) {
                if (!s_keep[j]) continue;
                u64 pk = s_pack[j];
                int myc = (int)(pk & 0x7F);
                u64 m = s_clsmask[myc];           // only same-class kept boxes
                if (!m) continue;                 // common case: no same-class keeper
                int o = (int)((pk >> 7) & 0x7FF);
                float4 bx = s_box[o];
                float off = (float)myc * 2.0f;
                float y1 = bx.x + off, x1 = bx.y + off, y2 = bx.z + off, x2 = bx.w + off;
                float ar = (y2 - y1) * (x2 - x1);
                int keep = 1;
                while (m) {
                    int kI = __ffsll((unsigned long long)m) - 1;
                    m &= m - 1;
                    float iy1 = s_cy1[kI], ix1 = s_cx1[kI];
                    float iy2 = s_cy2[kI], ix2 = s_cx2[kI];
                    float iar = s_car[kI];
                    float ih = fmaxf(fminf(y2, iy2) - fmaxf(y1, iy1), 0.0f);
                    float iw = fmaxf(fminf(x2, ix2) - fmaxf(x1, ix1), 0.0f);
                    float inter = ih * iw;
                    float iou = inter / ((ar + iar - inter) + 1e-8f);
                    if (iou > NMS_TAU) { keep = 0; break; }
                }
                if (!keep) s_keep[j] = 0;
            }
        }
        __syncthreads();
    }
    __syncthreads();

    // ---- rank kept entries via block prefix scan, scatter output ----
    int a0 = (int)s_keep[2 * tid], a1 = (int)s_keep[2 * tid + 1];
    int ssum = a0 + a1;
    int wid = tid >> 6;
    int v = ssum;
    for (int off = 1; off < 64; off <<= 1) {
        int n = __shfl_up(v, off);
        if (lane >= off) v += n;
    }
    if (lane == 63) s_scan[wid] = v;
    __syncthreads();
    if (tid == 0) {
        int acc = 0;
        for (int w2 = 0; w2 < 16; ++w2) { int t2 = s_scan[w2]; s_scan[w2] = acc; acc += t2; }
        s_scan[16] = acc;
    }
    __syncthreads();
    int incl = v + s_scan[wid];
    int excl0 = incl - ssum;
    int excl1 = excl0 + a0;

    float* ob = out + (size_t)b * (MAXDET * 6);
    for (int e = 0; e < 2; ++e) {
        int j = 2 * tid + e;
        int kp = e ? a1 : a0;
        int rk = e ? excl1 : excl0;
        if (kp && rk < MAXDET) {
            u64 pk = s_pack[j];
            int o = (int)((pk >> 7) & 0x7FF);
            int cl = (int)(pk & 0x7F);
            unsigned ip = ~(unsigned)(pk >> 32);
            unsigned kb = (ip & 0x80000000u) ? (ip & 0x7FFFFFFFu) : ~ip;
            float4 bx = s_box[o];
            float* row = ob + rk * 6;
            row[0] = bx.x; row[1] = bx.y; row[2] = bx.z; row[3] = bx.w;
            row[4] = (float)cl;
            row[5] = __uint_as_float(kb);
        }
    }
    int K = s_scan[16];
    if (K > MAXDET) K = MAXDET;
    for (int s0 = K + tid; s0 < MAXDET; s0 += 1024) {
        float* row = ob + s0 * 6;
#pragma unroll
        for (int q = 0; q < 6; ++q) row[q] = 0.0f;
    }
}

// ============ Fallback: fused single kernel (proven, ws-free) ============
__global__ __launch_bounds__(1024) void det_kernel(const float* __restrict__ rois,
                                                   const float* __restrict__ probs,
                                                   const float* __restrict__ deltas,
                                                   const float* __restrict__ meta,
                                                   float* __restrict__ out) {
#pragma clang fp contract(off)
    __shared__ float s_key[SORTN];
    __shared__ unsigned short s_idx[SORTN];
    __shared__ float4 s_box[NROI];
    __shared__ unsigned char s_cls[NROI];
    __shared__ unsigned char s_keep[SORTN];
    __shared__ float s_chunk[64 * 5];
    __shared__ int s_scan[17];
    __shared__ int s_nk, s_total, s_V;

    const int b = blockIdx.x;
    const int tid = threadIdx.x;

    const float sy = meta[4] - 1.0f;
    const float sx = meta[5] - 1.0f;
    const float* mb = meta + (size_t)b * META;
    const float wy1 = (mb[7] - 0.0f) / sy;
    const float wx1 = (mb[8] - 0.0f) / sx;
    const float wy2 = (mb[9] - 1.0f) / sy;
    const float wx2 = (mb[10] - 1.0f) / sx;

    for (int j = tid; j < SORTN; j += 1024) {
        s_idx[j] = (unsigned short)j;
        if (j >= NROI) { s_key[j] = -2.0f; continue; }
        const int t = b * NROI + j;
        const float* p = probs + (size_t)t * NCLS;
        float best = p[0];
        int bi = 0;
        for (int c = 1; c < NCLS; ++c) {
            float v = p[c];
            if (v > best) { best = v; bi = c; }
        }
        const float* dp = deltas + ((size_t)t * NCLS + bi) * 4;
        float d0 = dp[0] * 0.1f, d1 = dp[1] * 0.1f, d2 = dp[2] * 0.2f, d3 = dp[3] * 0.2f;
        const float* rp = rois + (size_t)t * 4;
        float r0 = rp[0], r1 = rp[1], r2 = rp[2], r3 = rp[3];
        float h = r2 - r0, w = r3 - r1;
        float cy = (r0 + 0.5f * h) + d0 * h;
        float cx = (r1 + 0.5f * w) + d1 * w;
        float h2 = h * expf(d2);
        float w2 = w * expf(d3);
        float y1 = cy - 0.5f * h2, x1 = cx - 0.5f * w2;
        float y2 = y1 + h2, x2 = x1 + w2;
        y1 = fminf(fmaxf(y1, wy1), wy2);
        x1 = fminf(fmaxf(x1, wx1), wx2);
        y2 = fminf(fmaxf(y2, wy1), wy2);
        x2 = fminf(fmaxf(x2, wx1), wx2);
        bool valid = (bi > 0) && (best >= MINCONF);
        s_key[j] = valid ? best : -1.0f;
        s_box[j] = make_float4(y1, x1, y2, x2);
        s_cls[j] = (unsigned char)bi;
    }
    __syncthreads();

    for (int k = 2; k <= SORTN; k <<= 1) {
        for (int jj = k >> 1; jj > 0; jj >>= 1) {
            for (int i = tid; i < SORTN; i += 1024) {
                int ixj = i ^ jj;
                if (ixj > i) {
                    float ka = s_key[i], kb = s_key[ixj];
                    unsigned short ia = s_idx[i], ib = s_idx[ixj];
                    bool b_prec_a = (kb > ka) || (kb == ka && ib < ia);
                    bool dir = ((i & k) == 0);
                    if (b_prec_a == dir) {
                        s_key[i] = kb; s_key[ixj] = ka;
                        s_idx[i] = ib; s_idx[ixj] = ia;
                    }
                }
            }
            __syncthreads();
        }
    }

    if (tid == 0) {
        int lo = 0, hi = SORTN;
        while (lo < hi) {
            int mid = (lo + hi) >> 1;
            if (s_key[mid] > 0.0f) lo = mid + 1; else hi = mid;
        }
        s_V = lo;
        s_total = 0;
    }
    __syncthreads();
    const int V = s_V;

    for (int j = tid; j < SORTN; j += 1024) s_keep[j] = (j < V) ? 1 : 0;
    __syncthreads();

    for (int c = 0; c < V; c += 64) {
        if (tid < 64) {
            int j = c + tid;
            int keep = 0;
            float y1 = 0.f, x1 = 0.f, y2 = 0.f, x2 = 0.f, ar = 0.f;
            if (j < V) {
                keep = (int)s_keep[j];
                int o = (int)s_idx[j];
                float4 bx = s_box[o];
                float off = (float)s_cls[o] * 2.0f;
                y1 = bx.x + off; x1 = bx.y + off; y2 = bx.z + off; x2 = bx.w + off;
                ar = (y2 - y1) * (x2 - x1);
            }
            for (int i = 0; i < 63; ++i) {
                int ki = __shfl(keep, i);
                float iy1 = __shfl(y1, i), ix1 = __shfl(x1, i);
                float iy2 = __shfl(y2, i), ix2 = __shfl(x2, i);
                float iar = __shfl(ar, i);
                if (tid > i && keep && ki) {
                    float ih = fmaxf(fminf(y2, iy2) - fmaxf(y1, iy1), 0.0f);
                    float iw = fmaxf(fminf(x2, ix2) - fmaxf(x1, ix1), 0.0f);
                    float inter = ih * iw;
                    float iou = inter / ((ar + iar - inter) + 1e-8f);
                    if (iou > NMS_TAU) keep = 0;
                }
            }
            if (j < V) s_keep[j] = (unsigned char)keep;
            unsigned long long bal = __ballot(keep && (j < V));
            int nk = __popcll(bal);
            if (keep && j < V) {
                int pos = __popcll(bal & ((1ULL << tid) - 1ULL));
                s_chunk[pos * 5 + 0] = y1; s_chunk[pos * 5 + 1] = x1;
                s_chunk[pos * 5 + 2] = y2; s_chunk[pos * 5 + 3] = x2;
                s_chunk[pos * 5 + 4] = ar;
            }
            if (tid == 0) { s_nk = nk; s_total += nk; }
        }
        __syncthreads();
        if (s_total >= MAXDET) break;
        int nk = s_nk;
        if (nk > 0) {
            for (int j = c + 64 + tid; j < V; j += 1024) {
                if (!s_keep[j]) continue;
                int o = (int)s_idx[j];
                float4 bx = s_box[o];
                float off = (float)s_cls[o] * 2.0f;
                float y1 = bx.x + off, x1 = bx.y + off, y2 = bx.z + off, x2 = bx.w + off;
                float ar = (y2 - y1) * (x2 - x1);
                int keep = 1;
                for (int kI = 0; kI < nk; ++kI) {
                    float iy1 = s_chunk[kI * 5 + 0], ix1 = s_chunk[kI * 5 + 1];
                    float iy2 = s_chunk[kI * 5 + 2], ix2 = s_chunk[kI * 5 + 3];
                    float iar = s_chunk[kI * 5 + 4];
                    float ih = fmaxf(fminf(y2, iy2) - fmaxf(y1, iy1), 0.0f);
                    float iw = fmaxf(fminf(x2, ix2) - fmaxf(x1, ix1), 0.0f);
                    float inter = ih * iw;
                    float iou = inter / ((ar + iar - inter) + 1e-8f);
                    if (iou > NMS_TAU) { keep = 0; break; }
                }
                if (!keep) s_keep[j] = 0;
            }
        }
        __syncthreads();
    }
    __syncthreads();

    int a0 = (int)s_keep[2 * tid], a1 = (int)s_keep[2 * tid + 1];
    int ssum = a0 + a1;
    int lane = tid & 63, wid = tid >> 6;
    int v = ssum;
    for (int off = 1; off < 64; off <<= 1) {
        int n = __shfl_up(v, off);
        if (lane >= off) v += n;
    }
    if (lane == 63) s_scan[wid] = v;
    __syncthreads();
    if (tid == 0) {
        int acc = 0;
        for (int wv = 0; wv < 16; ++wv) { int t2 = s_scan[wv]; s_scan[wv] = acc; acc += t2; }
        s_scan[16] = acc;
    }
    __syncthreads();
    int incl = v + s_scan[wid];
    int excl0 = incl - ssum;
    int excl1 = excl0 + a0;

    float* ob = out + (size_t)b * (MAXDET * 6);
    for (int e = 0; e < 2; ++e) {
        int j = 2 * tid + e;
        int kp = e ? a1 : a0;
        int rk = e ? excl1 : excl0;
        if (kp && rk < MAXDET) {
            int o = (int)s_idx[j];
            float4 bx = s_box[o];
            float* row = ob + rk * 6;
            row[0] = bx.x; row[1] = bx.y; row[2] = bx.z; row[3] = bx.w;
            row[4] = (float)s_cls[o];
            row[5] = s_key[j];
        }
    }
    int K = s_scan[16];
    if (K > MAXDET) K = MAXDET;
    for (int s0 = K + tid; s0 < MAXDET; s0 += 1024) {
        float* row = ob + s0 * 6;
#pragma unroll
        for (int q = 0; q < 6; ++q) row[q] = 0.0f;
    }
}

extern "C" void kernel_launch(void* const* d_in, const int* in_sizes, int n_in,
                              void* d_out, int out_size, void* d_ws, size_t ws_size,
                              hipStream_t stream) {
    const float* rois   = (const float*)d_in[0];
    const float* probs  = (const float*)d_in[1];
    const float* deltas = (const float*)d_in[2];
    const float* meta   = (const float*)d_in[3];
    float* out = (float*)d_out;

    int B = in_sizes[0] / (NROI * 4);
    int total = B * NROI;

    // ws layout: box[total] float4 | pack[B*2048] u64
    size_t need = (size_t)total * 16 + (size_t)B * SORTN * 8;
    if (ws_size >= need) {
        float4* wbox = (float4*)d_ws;
        u64*    wpack = (u64*)(wbox + total);
        refine_kernel<<<(total + 31) / 32, 256, 0, stream>>>(rois, probs, deltas, meta,
                                                             wbox, wpack, total);
        merge_nms_kernel<<<B, 1024, 0, stream>>>(wbox, wpack, out);
    } else {
        det_kernel<<<B, 1024, 0, stream>>>(rois, probs, deltas, meta, out);
    }
}

// Round 9
// 94.316 us; speedup vs baseline: 1.0073x; 1.0073x over previous
//
#include <hip/hip_runtime.h>
#include <cfloat>
#include <cmath>

#define NROI 2000
#define NCLS 81
#define META 93
#define NMS_TAU 0.3f
#define MINCONF 0.7f
#define MAXDET 100
#define SORTN 2048

typedef unsigned long long u64;

// pack layout: [63:32]=dk (ascending == score descending), [17:7]=roi idx, [6:0]=class
// idx more significant than cls -> tie order identical to (key desc, idx asc).
#define PADPACK(j) (0xC000000000000000ull | (u64)((unsigned)(j) << 7))

// ============ Kernel A: per-roi refine, 1 thread per roi, full-unroll argmax ============
__global__ __launch_bounds__(256) void refine_kernel(const float* __restrict__ rois,
                                                     const float* __restrict__ probs,
                                                     const float* __restrict__ deltas,
                                                     const float* __restrict__ meta,
                                                     float4* __restrict__ wbox,
                                                     u64* __restrict__ wpack,
                                                     int total) {
#pragma clang fp contract(off)
    const int t = blockIdx.x * 256 + threadIdx.x;
    if (t >= total) return;
    const int b = t / NROI;
    const int j = t - b * NROI;

    // argmax over 81 classes: fully unrolled -> all loads independent (deep MLP),
    // strict > with ascending c == first-max-wins (jnp.argmax)
    const float* p = probs + (size_t)t * NCLS;
    float best = p[0];
    int bi = 0;
#pragma unroll
    for (int c = 1; c < NCLS; ++c) {
        float v = p[c];
        if (v > best) { best = v; bi = c; }
    }

    const float* dp = deltas + ((size_t)t * NCLS + bi) * 4;   // 16B-aligned
    float4 dd = *(const float4*)dp;
    float d0 = dd.x * 0.1f, d1 = dd.y * 0.1f, d2 = dd.z * 0.2f, d3 = dd.w * 0.2f;
    float4 rr = *(const float4*)(rois + (size_t)t * 4);
    float r0 = rr.x, r1 = rr.y, r2 = rr.z, r3 = rr.w;
    float h = r2 - r0, w = r3 - r1;
    float cy = (r0 + 0.5f * h) + d0 * h;
    float cx = (r1 + 0.5f * w) + d1 * w;
    float h2 = h * expf(d2);
    float w2 = w * expf(d3);
    float y1 = cy - 0.5f * h2, x1 = cx - 0.5f * w2;
    float y2 = y1 + h2, x2 = x1 + w2;

    const float sy = meta[4] - 1.0f;
    const float sx = meta[5] - 1.0f;
    const float* mb = meta + (size_t)b * META;
    const float wy1 = (mb[7] - 0.0f) / sy;
    const float wx1 = (mb[8] - 0.0f) / sx;
    const float wy2 = (mb[9] - 1.0f) / sy;
    const float wx2 = (mb[10] - 1.0f) / sx;
    y1 = fminf(fmaxf(y1, wy1), wy2);
    x1 = fminf(fmaxf(x1, wx1), wx2);
    y2 = fminf(fmaxf(y2, wy1), wy2);
    x2 = fminf(fmaxf(x2, wx1), wx2);

    bool valid = (bi > 0) && (best >= MINCONF);
    float key = valid ? best : -1.0f;
    unsigned kb = __float_as_uint(key);
    unsigned ip = (kb & 0x80000000u) ? ~kb : (kb | 0x80000000u);
    unsigned dk = ~ip;                          // ascending dk == descending key
    wbox[t] = make_float4(y1, x1, y2, x2);
    wpack[(size_t)b * SORTN + j] = ((u64)dk << 32) | (unsigned)(j << 7) | (unsigned)bi;
}

// ============ Kernel B: register sort + rank-merge + pairwise NMS + top-k ============
__global__ __launch_bounds__(1024) void merge_nms_kernel(const float4* __restrict__ wbox,
                                                         const u64* __restrict__ wpack,
                                                         float* __restrict__ out) {
#pragma clang fp contract(off)
    __shared__ u64 s_pack[SORTN];                 // 16 KB
    __shared__ float4 s_boxArena[NROI];           // 32 KB (aliased as merge temp)
    __shared__ unsigned char s_keep[SORTN];       // 2 KB
    // chunk-candidate staging (SoA, conflict-free lane reads)
    __shared__ float s_cy1[64], s_cx1[64], s_cy2[64], s_cx2[64], s_car[64];
    __shared__ int s_ccl[64], s_init[64];
    __shared__ u64 s_sup[64];
    __shared__ u64 s_clsmask[NCLS];               // per-class alive bitmask
    __shared__ u64 s_alive;
    __shared__ int s_scan[17];
    __shared__ int s_total, s_V;

    u64* s_tmp = (u64*)s_boxArena;                // alias, used pre-box-load
    float4* s_box = s_boxArena;

    const int b = blockIdx.x;
    const int tid = threadIdx.x;
    const int lane = tid & 63;
    const int wv = tid >> 6;                      // wave id 0..15

    // ---- register-prefetch boxes (HBM latency overlaps sort+merge below) ----
    float4 rb0 = wbox[b * NROI + tid];            // tid < 1024 < NROI always
    float4 rb1;
    const int bj1 = tid + 1024;
    if (bj1 < NROI) rb1 = wbox[b * NROI + bj1];

    // ---- load 2 packed keys/thread: elements g0=128*wv+2*lane, g1=g0+1 ----
    const u64* wp = wpack + (size_t)b * SORTN;
    const int g0 = (wv << 7) + (lane << 1);
    const int g1 = g0 + 1;
    u64 v0, v1;
    if (wv < 15) {                                // wave-uniform: no pads here
        ulonglong2 ld = *(const ulonglong2*)(wp + g0);
        v0 = ld.x; v1 = ld.y;
    } else {
        v0 = (g0 < NROI) ? wp[g0] : PADPACK(g0);
        v1 = (g1 < NROI) ? wp[g1] : PADPACK(g1);
    }

    // ---- wave-local register bitonic: each wave sorts its 128-run ascending ----
    for (int k = 2; k <= 128; k <<= 1) {
        const bool asc = ((lane & (k >> 1)) == 0);
        for (int jj = k >> 1; jj >= 2; jj >>= 1) {
            const int d = jj >> 1;
            u64 p0 = __shfl_xor(v0, d);
            u64 p1 = __shfl_xor(v1, d);
            const bool lower = ((lane & d) == 0);
            const bool keepmin = (lower == asc);
            v0 = ((v0 < p0) == keepmin) ? v0 : p0;
            v1 = ((v1 < p1) == keepmin) ? v1 : p1;
        }
        u64 lo = (v0 < v1) ? v0 : v1;
        u64 hi = (v0 < v1) ? v1 : v0;
        v0 = asc ? lo : hi;
        v1 = asc ? hi : lo;
    }
    s_pack[g0] = v0;
    s_pack[g1] = v1;
    __syncthreads();

    // ---- rank-merge rounds: 128 -> 256 -> 512 -> 1024 -> 2048 (ping-pong) ----
    // keys unique (idx in low bits) -> strict lower_bound is collision-free.
    {
        u64* src = s_pack;
        u64* dst = s_tmp;
#pragma unroll
        for (int s = 7; s <= 10; ++s) {           // L = 1<<s
            const int L = 1 << s;
            for (int i = tid; i < SORTN; i += 1024) {
                u64 x = src[i];
                int run = i >> s, local = i & (L - 1);
                int pbase = (run ^ 1) << s;
                int lo = 0, hi = L;
                while (lo < hi) {
                    int mid = (lo + hi) >> 1;
                    if (src[pbase + mid] < x) lo = mid + 1; else hi = mid;
                }
                dst[((run >> 1) << (s + 1)) + local + lo] = x;
            }
            __syncthreads();
            u64* t2 = src; src = dst; dst = t2;
        }
        // 4 rounds (even) -> final data back in s_pack
    }

    // ---- store prefetched boxes; PARALLEL V-find fused with keep-init ----
    s_box[tid] = rb0;
    if (bj1 < NROI) s_box[bj1] = rb1;
    if (tid == 0) {
        s_total = 0;
        if (s_pack[0] >> 63) s_V = 0;             // no valid entries at all
    }
    for (int j = tid; j < SORTN; j += 1024) {
        bool va = !(s_pack[j] >> 63);             // sorted: valid prefix
        bool vb = (j + 1 < SORTN) ? !(s_pack[j + 1] >> 63) : false;
        if (va && !vb) s_V = j + 1;               // exactly one writer
        s_keep[j] = va ? 1 : 0;                   // keep-init == validity prefix
    }
    __syncthreads();
    const int V = s_V;

    // ---- blocked greedy NMS: pairwise matrix + sparse exact resolve ----
    // class-skip is EXACT: different classes have offset diff >= 2 while
    // clipped boxes lie in [0,1] -> intersection height <= -1 -> IoU == 0.
    for (int c = 0; c < V; c += 64) {
        bool init_flag = false;
        if (tid < 64) {
            int j = c + tid;
            int cl = -1;
            float y1 = 0.f, x1 = 0.f, y2 = 0.f, x2 = 0.f, ar = 0.f;
            if (j < V) {
                init_flag = (s_keep[j] != 0);
                u64 pk = s_pack[j];
                int o = (int)((pk >> 7) & 0x7FF);
                cl = (int)(pk & 0x7F);
                float4 bx = s_box[o];
                float off = (float)cl * 2.0f;
                // area from OFFSETTED coords (matches reference fp rounding)
                y1 = bx.x + off; x1 = bx.y + off; y2 = bx.z + off; x2 = bx.w + off;
                ar = (y2 - y1) * (x2 - x1);
            }
            s_cy1[tid] = y1; s_cx1[tid] = x1; s_cy2[tid] = y2; s_cx2[tid] = x2;
            s_car[tid] = ar; s_ccl[tid] = cl; s_init[tid] = init_flag ? 1 : 0;
        } else if (tid >= 64 && tid < 64 + NCLS) {
            s_clsmask[tid - 64] = 0ull;           // zero class masks in parallel
        }
        __syncthreads();

        // pairwise suppression matrix: wave w handles rows w, w+16, w+32, w+48
        {
            int i = tid & 63;
            int w = tid >> 6;
            float iy1 = s_cy1[i], ix1 = s_cx1[i], iy2 = s_cy2[i], ix2 = s_cx2[i];
            float iar = s_car[i];
            int icl = s_ccl[i], iin = s_init[i];
#pragma unroll
            for (int p = 0; p < 4; ++p) {
                int jr = w + (p << 4);
                float jy1 = s_cy1[jr], jx1 = s_cx1[jr], jy2 = s_cy2[jr], jx2 = s_cx2[jr];
                float jar = s_car[jr];
                int jcl = s_ccl[jr], jin = s_init[jr];
                bool bit = false;
                if (i < jr && iin && jin && icl == jcl) {
                    float ih = fmaxf(fminf(jy2, iy2) - fmaxf(jy1, iy1), 0.0f);
                    float iw = fmaxf(fminf(jx2, ix2) - fmaxf(jx1, ix1), 0.0f);
                    float inter = ih * iw;
                    float iou = inter / ((jar + iar - inter) + 1e-8f);
                    bit = iou > NMS_TAU;
                }
                u64 m = __ballot(bit);
                if (i == 0) s_sup[jr] = m;
            }
        }
        __syncthreads();

        // exact sequential resolve on wave 0 (sparse fast path) + class masks
        if (tid < 64) {
            u64 sup = s_sup[tid];
            u64 initm = __ballot(init_flag);
            u64 hasup = __ballot(init_flag && sup != 0ull);
            u64 alive = initm & ~hasup;          // no-suppressor entries kept outright
            u64 m = hasup;
            while (m) {                           // usually 0-4 iterations
                int t2 = __ffsll((unsigned long long)m) - 1;
                m &= m - 1;
                u64 st = __shfl(sup, t2);         // sup_t only has bits < t2
                if ((st & alive) == 0ull) alive |= (1ull << t2);
            }
            s_keep[c + tid] = (unsigned char)((alive >> tid) & 1ull);
            if ((alive >> tid) & 1ull)
                atomicOr(&s_clsmask[s_ccl[tid]], 1ull << tid);
            if (tid == 0) { s_alive = alive; s_total += __popcll(alive); }
        }
        __syncthreads();
        if (s_total >= MAXDET) break;  // tail ranks >= 100, never output

        // suppress remaining entries against this chunk's kept set
        if (s_alive) {
            for (int j = c + 64 + tid; j < V; j += 1024) {
                if (!s_keep[j]) continue;
                u64 pk = s_pack[j];
                int myc = (int)(pk & 0x7F);
                u64 m = s_clsmask[myc];           // only same-class kept boxes
                if (!m) continue;                 // common case: no same-class keeper
                int o = (int)((pk >> 7) & 0x7FF);
                float4 bx = s_box[o];
                float off = (float)myc * 2.0f;
                float y1 = bx.x + off, x1 = bx.y + off, y2 = bx.z + off, x2 = bx.w + off;
                float ar = (y2 - y1) * (x2 - x1);
                int keep = 1;
                while (m) {
                    int kI = __ffsll((unsigned long long)m) - 1;
                    m &= m - 1;
                    float iy1 = s_cy1[kI], ix1 = s_cx1[kI];
                    float iy2 = s_cy2[kI], ix2 = s_cx2[kI];
                    float iar = s_car[kI];
                    float ih = fmaxf(fminf(y2, iy2) - fmaxf(y1, iy1), 0.0f);
                    float iw = fmaxf(fminf(x2, ix2) - fmaxf(x1, ix1), 0.0f);
                    float inter = ih * iw;
                    float iou = inter / ((ar + iar - inter) + 1e-8f);
                    if (iou > NMS_TAU) { keep = 0; break; }
                }
                if (!keep) s_keep[j] = 0;
            }
        }
        __syncthreads();
    }
    __syncthreads();

    // ---- rank kept entries via block prefix scan, scatter output ----
    int a0 = (int)s_keep[2 * tid], a1 = (int)s_keep[2 * tid + 1];
    int ssum = a0 + a1;
    int wid = tid >> 6;
    int v = ssum;
    for (int off = 1; off < 64; off <<= 1) {
        int n = __shfl_up(v, off);
        if (lane >= off) v += n;
    }
    if (lane == 63) s_scan[wid] = v;
    __syncthreads();
    if (tid == 0) {
        int acc = 0;
        for (int w2 = 0; w2 < 16; ++w2) { int t2 = s_scan[w2]; s_scan[w2] = acc; acc += t2; }
        s_scan[16] = acc;
    }
    __syncthreads();
    int incl = v + s_scan[wid];
    int excl0 = incl - ssum;
    int excl1 = excl0 + a0;

    float* ob = out + (size_t)b * (MAXDET * 6);
    for (int e = 0; e < 2; ++e) {
        int j = 2 * tid + e;
        int kp = e ? a1 : a0;
        int rk = e ? excl1 : excl0;
        if (kp && rk < MAXDET) {
            u64 pk = s_pack[j];
            int o = (int)((pk >> 7) & 0x7FF);
            int cl = (int)(pk & 0x7F);
            unsigned ip = ~(unsigned)(pk >> 32);
            unsigned kb = (ip & 0x80000000u) ? (ip & 0x7FFFFFFFu) : ~ip;
            float4 bx = s_box[o];
            float* row = ob + rk * 6;
            row[0] = bx.x; row[1] = bx.y; row[2] = bx.z; row[3] = bx.w;
            row[4] = (float)cl;
            row[5] = __uint_as_float(kb);
        }
    }
    int K = s_scan[16];
    if (K > MAXDET) K = MAXDET;
    for (int s0 = K + tid; s0 < MAXDET; s0 += 1024) {
        float* row = ob + s0 * 6;
#pragma unroll
        for (int q = 0; q < 6; ++q) row[q] = 0.0f;
    }
}

// ============ Fallback: fused single kernel (proven, ws-free) ============
__global__ __launch_bounds__(1024) void det_kernel(const float* __restrict__ rois,
                                                   const float* __restrict__ probs,
                                                   const float* __restrict__ deltas,
                                                   const float* __restrict__ meta,
                                                   float* __restrict__ out) {
#pragma clang fp contract(off)
    __shared__ float s_key[SORTN];
    __shared__ unsigned short s_idx[SORTN];
    __shared__ float4 s_box[NROI];
    __shared__ unsigned char s_cls[NROI];
    __shared__ unsigned char s_keep[SORTN];
    __shared__ float s_chunk[64 * 5];
    __shared__ int s_scan[17];
    __shared__ int s_nk, s_total, s_V;

    const int b = blockIdx.x;
    const int tid = threadIdx.x;

    const float sy = meta[4] - 1.0f;
    const float sx = meta[5] - 1.0f;
    const float* mb = meta + (size_t)b * META;
    const float wy1 = (mb[7] - 0.0f) / sy;
    const float wx1 = (mb[8] - 0.0f) / sx;
    const float wy2 = (mb[9] - 1.0f) / sy;
    const float wx2 = (mb[10] - 1.0f) / sx;

    for (int j = tid; j < SORTN; j += 1024) {
        s_idx[j] = (unsigned short)j;
        if (j >= NROI) { s_key[j] = -2.0f; continue; }
        const int t = b * NROI + j;
        const float* p = probs + (size_t)t * NCLS;
        float best = p[0];
        int bi = 0;
        for (int c = 1; c < NCLS; ++c) {
            float v = p[c];
            if (v > best) { best = v; bi = c; }
        }
        const float* dp = deltas + ((size_t)t * NCLS + bi) * 4;
        float d0 = dp[0] * 0.1f, d1 = dp[1] * 0.1f, d2 = dp[2] * 0.2f, d3 = dp[3] * 0.2f;
        const float* rp = rois + (size_t)t * 4;
        float r0 = rp[0], r1 = rp[1], r2 = rp[2], r3 = rp[3];
        float h = r2 - r0, w = r3 - r1;
        float cy = (r0 + 0.5f * h) + d0 * h;
        float cx = (r1 + 0.5f * w) + d1 * w;
        float h2 = h * expf(d2);
        float w2 = w * expf(d3);
        float y1 = cy - 0.5f * h2, x1 = cx - 0.5f * w2;
        float y2 = y1 + h2, x2 = x1 + w2;
        y1 = fminf(fmaxf(y1, wy1), wy2);
        x1 = fminf(fmaxf(x1, wx1), wx2);
        y2 = fminf(fmaxf(y2, wy1), wy2);
        x2 = fminf(fmaxf(x2, wx1), wx2);
        bool valid = (bi > 0) && (best >= MINCONF);
        s_key[j] = valid ? best : -1.0f;
        s_box[j] = make_float4(y1, x1, y2, x2);
        s_cls[j] = (unsigned char)bi;
    }
    __syncthreads();

    for (int k = 2; k <= SORTN; k <<= 1) {
        for (int jj = k >> 1; jj > 0; jj >>= 1) {
            for (int i = tid; i < SORTN; i += 1024) {
                int ixj = i ^ jj;
                if (ixj > i) {
                    float ka = s_key[i], kb = s_key[ixj];
                    unsigned short ia = s_idx[i], ib = s_idx[ixj];
                    bool b_prec_a = (kb > ka) || (kb == ka && ib < ia);
                    bool dir = ((i & k) == 0);
                    if (b_prec_a == dir) {
                        s_key[i] = kb; s_key[ixj] = ka;
                        s_idx[i] = ib; s_idx[ixj] = ia;
                    }
                }
            }
            __syncthreads();
        }
    }

    if (tid == 0) {
        int lo = 0, hi = SORTN;
        while (lo < hi) {
            int mid = (lo + hi) >> 1;
            if (s_key[mid] > 0.0f) lo = mid + 1; else hi = mid;
        }
        s_V = lo;
        s_total = 0;
    }
    __syncthreads();
    const int V = s_V;

    for (int j = tid; j < SORTN; j += 1024) s_keep[j] = (j < V) ? 1 : 0;
    __syncthreads();

    for (int c = 0; c < V; c += 64) {
        if (tid < 64) {
            int j = c + tid;
            int keep = 0;
            float y1 = 0.f, x1 = 0.f, y2 = 0.f, x2 = 0.f, ar = 0.f;
            if (j < V) {
                keep = (int)s_keep[j];
                int o = (int)s_idx[j];
                float4 bx = s_box[o];
                float off = (float)s_cls[o] * 2.0f;
                y1 = bx.x + off; x1 = bx.y + off; y2 = bx.z + off; x2 = bx.w + off;
                ar = (y2 - y1) * (x2 - x1);
            }
            for (int i = 0; i < 63; ++i) {
                int ki = __shfl(keep, i);
                float iy1 = __shfl(y1, i), ix1 = __shfl(x1, i);
                float iy2 = __shfl(y2, i), ix2 = __shfl(x2, i);
                float iar = __shfl(ar, i);
                if (tid > i && keep && ki) {
                    float ih = fmaxf(fminf(y2, iy2) - fmaxf(y1, iy1), 0.0f);
                    float iw = fmaxf(fminf(x2, ix2) - fmaxf(x1, ix1), 0.0f);
                    float inter = ih * iw;
                    float iou = inter / ((ar + iar - inter) + 1e-8f);
                    if (iou > NMS_TAU) keep = 0;
                }
            }
            if (j < V) s_keep[j] = (unsigned char)keep;
            unsigned long long bal = __ballot(keep && (j < V));
            int nk = __popcll(bal);
            if (keep && j < V) {
                int pos = __popcll(bal & ((1ULL << tid) - 1ULL));
                s_chunk[pos * 5 + 0] = y1; s_chunk[pos * 5 + 1] = x1;
                s_chunk[pos * 5 + 2] = y2; s_chunk[pos * 5 + 3] = x2;
                s_chunk[pos * 5 + 4] = ar;
            }
            if (tid == 0) { s_nk = nk; s_total += nk; }
        }
        __syncthreads();
        if (s_total >= MAXDET) break;
        int nk = s_nk;
        if (nk > 0) {
            for (int j = c + 64 + tid; j < V; j += 1024) {
                if (!s_keep[j]) continue;
                int o = (int)s_idx[j];
                float4 bx = s_box[o];
                float off = (float)s_cls[o] * 2.0f;
                float y1 = bx.x + off, x1 = bx.y + off, y2 = bx.z + off, x2 = bx.w + off;
                float ar = (y2 - y1) * (x2 - x1);
                int keep = 1;
                for (int kI = 0; kI < nk; ++kI) {
                    float iy1 = s_chunk[kI * 5 + 0], ix1 = s_chunk[kI * 5 + 1];
                    float iy2 = s_chunk[kI * 5 + 2], ix2 = s_chunk[kI * 5 + 3];
                    float iar = s_chunk[kI * 5 + 4];
                    float ih = fmaxf(fminf(y2, iy2) - fmaxf(y1, iy1), 0.0f);
                    float iw = fmaxf(fminf(x2, ix2) - fmaxf(x1, ix1), 0.0f);
                    float inter = ih * iw;
                    float iou = inter / ((ar + iar - inter) + 1e-8f);
                    if (iou > NMS_TAU) { keep = 0; break; }
                }
                if (!keep) s_keep[j] = 0;
            }
        }
        __syncthreads();
    }
    __syncthreads();

    int a0 = (int)s_keep[2 * tid], a1 = (int)s_keep[2 * tid + 1];
    int ssum = a0 + a1;
    int lane = tid & 63, wid = tid >> 6;
    int v = ssum;
    for (int off = 1; off < 64; off <<= 1) {
        int n = __shfl_up(v, off);
        if (lane >= off) v += n;
    }
    if (lane == 63) s_scan[wid] = v;
    __syncthreads();
    if (tid == 0) {
        int acc = 0;
        for (int wv = 0; wv < 16; ++wv) { int t2 = s_scan[wv]; s_scan[wv] = acc; acc += t2; }
        s_scan[16] = acc;
    }
    __syncthreads();
    int incl = v + s_scan[wid];
    int excl0 = incl - ssum;
    int excl1 = excl0 + a0;

    float* ob = out + (size_t)b * (MAXDET * 6);
    for (int e = 0; e < 2; ++e) {
        int j = 2 * tid + e;
        int kp = e ? a1 : a0;
        int rk = e ? excl1 : excl0;
        if (kp && rk < MAXDET) {
            int o = (int)s_idx[j];
            float4 bx = s_box[o];
            float* row = ob + rk * 6;
            row[0] = bx.x; row[1] = bx.y; row[2] = bx.z; row[3] = bx.w;
            row[4] = (float)s_cls[o];
            row[5] = s_key[j];
        }
    }
    int K = s_scan[16];
    if (K > MAXDET) K = MAXDET;
    for (int s0 = K + tid; s0 < MAXDET; s0 += 1024) {
        float* row = ob + s0 * 6;
#pragma unroll
        for (int q = 0; q < 6; ++q) row[q] = 0.0f;
    }
}

extern "C" void kernel_launch(void* const* d_in, const int* in_sizes, int n_in,
                              void* d_out, int out_size, void* d_ws, size_t ws_size,
                              hipStream_t stream) {
    const float* rois   = (const float*)d_in[0];
    const float* probs  = (const float*)d_in[1];
    const float* deltas = (const float*)d_in[2];
    const float* meta   = (const float*)d_in[3];
    float* out = (float*)d_out;

    int B = in_sizes[0] / (NROI * 4);
    int total = B * NROI;

    // ws layout: box[total] float4 | pack[B*2048] u64
    size_t need = (size_t)total * 16 + (size_t)B * SORTN * 8;
    if (ws_size >= need) {
        float4* wbox = (float4*)d_ws;
        u64*    wpack = (u64*)(wbox + total);
        refine_kernel<<<(total + 255) / 256, 256, 0, stream>>>(rois, probs, deltas, meta,
                                                               wbox, wpack, total);
        merge_nms_kernel<<<B, 1024, 0, stream>>>(wbox, wpack, out);
    } else {
        det_kernel<<<B, 1024, 0, stream>>>(rois, probs, deltas, meta, out);
    }
}